// Round 9
// baseline (163.153 us; speedup 1.0000x reference)
//
#include <hip/hip_runtime.h>
#include <hip/hip_bf16.h>

// Problem constants (fixed by reference): B=4, C=256, N=2048, H=8, D=32
#define Bx 4
#define Cx 256
#define Nx 2048
#define Hx 8
#define Dx 32

typedef __attribute__((ext_vector_type(8))) short bf16x8;   // 8 bf16 (4 VGPRs)
typedef __attribute__((ext_vector_type(4))) float f32x4;

// attention scale folded with log2(e) so softmax can use native exp2:
// (1/sqrt(32)) * 1.4426950408889634
#define QSCALE 0.25503494f

static __device__ __forceinline__ unsigned short f2bf(float f) {
    // round-to-nearest-even bf16
    unsigned int u = __float_as_uint(f);
    u += 0x7fffu + ((u >> 16) & 1u);
    return (unsigned short)(u >> 16);
}
static __device__ __forceinline__ float bf2f(unsigned short u) {
    return __uint_as_float(((unsigned int)u) << 16);
}
// raw hardware exp2 / rcp (no libm range fixup)
static __device__ __forceinline__ float fexp2(float x) {
    float r;
    asm("v_exp_f32 %0, %1" : "=v"(r) : "v"(x));
    return r;
}
static __device__ __forceinline__ float frcp(float x) {
    float r;
    asm("v_rcp_f32 %0, %1" : "=v"(r) : "v"(x));
    return r;
}

// ---------------------------------------------------------------------------
// Kernel 0: convert inputs to bf16 MFMA layouts.
//   blocks 0..511  : Xt[b][n][c] = bf16(x[b][c][n])  (transpose; 16 c/thread)
//   blocks 512..639: Wqkvb = bf16(w_qkv) (Q rows pre-scaled), Wpb = bf16(w_proj)
// ---------------------------------------------------------------------------
__global__ __launch_bounds__(256) void convert_kernel(
    const float* __restrict__ x, const float* __restrict__ w_qkv,
    const float* __restrict__ w_proj,
    unsigned short* __restrict__ Xt, unsigned short* __restrict__ Wqkvb,
    unsigned short* __restrict__ Wpb)
{
    const int bx = blockIdx.x, t = threadIdx.x;
    if (bx < 512) {
        const int nb = (bx & 31) * 256 + t;      // 0..8191 over (b,n)
        const int b = nb >> 11, n = nb & 2047;
        const int c0 = (bx >> 5) * 16;           // 16 c-groups
        const float* xb = x + (size_t)b * Cx * Nx + n;
        unsigned short* dst = Xt + ((size_t)b * Nx + n) * Cx;
        #pragma unroll
        for (int c8 = 0; c8 < 16; c8 += 8) {
            float f[8];
            #pragma unroll
            for (int j = 0; j < 8; ++j) f[j] = xb[(size_t)(c0 + c8 + j) * Nx];
            uint4 pk;
            pk.x = (unsigned)f2bf(f[0]) | ((unsigned)f2bf(f[1]) << 16);
            pk.y = (unsigned)f2bf(f[2]) | ((unsigned)f2bf(f[3]) << 16);
            pk.z = (unsigned)f2bf(f[4]) | ((unsigned)f2bf(f[5]) << 16);
            pk.w = (unsigned)f2bf(f[6]) | ((unsigned)f2bf(f[7]) << 16);
            *(uint4*)&dst[c0 + c8] = pk;
        }
    } else {
        const int flat = (bx - 512) * 2048 + t * 8;
        #pragma unroll
        for (int hh = 0; hh < 8; hh += 4) {
            const int f0 = flat + hh;
            if (f0 < 768 * 256) {
                const float sc = (f0 < 65536) ? QSCALE : 1.0f;
                const float4 f = *(const float4*)&w_qkv[f0];
                ushort4 o;
                o.x = f2bf(f.x * sc); o.y = f2bf(f.y * sc);
                o.z = f2bf(f.z * sc); o.w = f2bf(f.w * sc);
                *(ushort4*)&Wqkvb[f0] = o;
            } else {
                const int f2v = f0 - 768 * 256;
                const float4 f = *(const float4*)&w_proj[f2v];
                ushort4 o;
                o.x = f2bf(f.x); o.y = f2bf(f.y);
                o.z = f2bf(f.z); o.w = f2bf(f.w);
                *(ushort4*)&Wpb[f2v] = o;
            }
        }
    }
}

// ---------------------------------------------------------------------------
// Kernel 1: QKV projection, MFMA, register-direct (no LDS).  (unchanged)
// grid (12, 16, 4), 4 waves; wave tile = 32o x 64n (3 waves/SIMD).
// XCD-bijective swizzle: all o-tiles of one (n-tile,b) land on one XCD.
// ---------------------------------------------------------------------------
__global__ __launch_bounds__(256) void qkv_kernel(
    const unsigned short* __restrict__ Wb, const unsigned short* __restrict__ Xt,
    const float* __restrict__ bias,
    unsigned short* __restrict__ Qb, unsigned short* __restrict__ Kb,
    unsigned short* __restrict__ Vb)
{
    const int t = threadIdx.x;
    const int wv = t >> 6, l = t & 63;
    const int g = l >> 4, c = l & 15;

    const int lin = blockIdx.x + 12 * (blockIdx.y + 16 * blockIdx.z);
    const int xcd = lin & 7, s = lin >> 3;          // s in 0..95
    const int xb = s % 12;
    const int yz = (s / 12) * 8 + xcd;              // 0..63
    const int yb = yz & 15, b = yz >> 4;

    const int o0 = xb * 64 + (wv >> 1) * 32;
    const int n0 = yb * 128 + (wv & 1) * 64;
    const int region = xb >> 2;                     // 0=Q, 1=K, 2=V

    const unsigned short* XtB = Xt + (size_t)b * Nx * Cx;

    if (region < 2) {
        f32x4 acc[2][4];
        #pragma unroll
        for (int i = 0; i < 2; ++i)
            #pragma unroll
            for (int j = 0; j < 4; ++j) acc[i][j] = (f32x4){0.f, 0.f, 0.f, 0.f};

        for (int cc = 0; cc < Cx; cc += 32) {
            bf16x8 wf[2], xf[4];
            #pragma unroll
            for (int ti = 0; ti < 2; ++ti)
                wf[ti] = *(const bf16x8*)&Wb[(size_t)(o0 + ti * 16 + c) * Cx + cc + g * 8];
            #pragma unroll
            for (int tj = 0; tj < 4; ++tj)
                xf[tj] = *(const bf16x8*)&XtB[(size_t)(n0 + tj * 16 + c) * Cx + cc + g * 8];
            #pragma unroll
            for (int ti = 0; ti < 2; ++ti)
                #pragma unroll
                for (int tj = 0; tj < 4; ++tj)
                    acc[ti][tj] = __builtin_amdgcn_mfma_f32_16x16x32_bf16(
                        wf[ti], xf[tj], acc[ti][tj], 0, 0, 0);
        }

        unsigned short* dst = (region == 0) ? Qb : Kb;
        #pragma unroll
        for (int ti = 0; ti < 2; ++ti) {
            const int o = o0 + ti * 16 + g * 4;
            float4 bv = *(const float4*)&bias[o];
            if (region == 0) { bv.x *= QSCALE; bv.y *= QSCALE; bv.z *= QSCALE; bv.w *= QSCALE; }
            const int d0 = o & 31, bh = b * 8 + ((o >> 5) & 7);
            unsigned short* dp = dst + (size_t)bh * Nx * Dx + d0;
            #pragma unroll
            for (int tj = 0; tj < 4; ++tj) {
                const int n = n0 + tj * 16 + c;
                ushort4 w4;
                w4.x = f2bf(acc[ti][tj][0] + bv.x);
                w4.y = f2bf(acc[ti][tj][1] + bv.y);
                w4.z = f2bf(acc[ti][tj][2] + bv.z);
                w4.w = f2bf(acc[ti][tj][3] + bv.w);
                *(ushort4*)&dp[(size_t)n * Dx] = w4;
            }
        }
    } else {
        f32x4 acc[4][2];
        #pragma unroll
        for (int i = 0; i < 4; ++i)
            #pragma unroll
            for (int j = 0; j < 2; ++j) acc[i][j] = (f32x4){0.f, 0.f, 0.f, 0.f};

        for (int cc = 0; cc < Cx; cc += 32) {
            bf16x8 wf[2], xf[4];
            #pragma unroll
            for (int ot = 0; ot < 2; ++ot)
                wf[ot] = *(const bf16x8*)&Wb[(size_t)(o0 + ot * 16 + c) * Cx + cc + g * 8];
            #pragma unroll
            for (int nt = 0; nt < 4; ++nt)
                xf[nt] = *(const bf16x8*)&XtB[(size_t)(n0 + nt * 16 + c) * Cx + cc + g * 8];
            #pragma unroll
            for (int nt = 0; nt < 4; ++nt)
                #pragma unroll
                for (int ot = 0; ot < 2; ++ot)
                    acc[nt][ot] = __builtin_amdgcn_mfma_f32_16x16x32_bf16(
                        xf[nt], wf[ot], acc[nt][ot], 0, 0, 0);
        }

        #pragma unroll
        for (int ot = 0; ot < 2; ++ot) {
            const int o = o0 + ot * 16 + c;                   // 512..767
            const float bv = bias[o];
            const int oV = o - 512, d = oV & 31, bh = b * 8 + (oV >> 5);
            unsigned short* dp = Vb + ((size_t)bh * Dx + d) * Nx;
            #pragma unroll
            for (int nt = 0; nt < 4; ++nt) {
                const int n = n0 + nt * 16 + g * 4;
                ushort4 w4;
                w4.x = f2bf(acc[nt][ot][0] + bv);
                w4.y = f2bf(acc[nt][ot][1] + bv);
                w4.z = f2bf(acc[nt][ot][2] + bv);
                w4.w = f2bf(acc[nt][ot][3] + bv);
                *(ushort4*)&dp[n] = w4;
            }
        }
    }
}

// ---------------------------------------------------------------------------
// attn tile compute: S^T = K·Q^T, online softmax (defer-max, raw exp2,
// l via MFMA ones-trick), O^T += V^T·P^T.  All register-resident.
// ---------------------------------------------------------------------------
static __device__ __forceinline__ void attn_tile(
    const bf16x8* kf, const bf16x8* vf, const bf16x8* qf, bf16x8 onesv,
    f32x4 (&oacc)[2][2], f32x4 (&lacc)[2], float (&m_i)[2])
{
    const f32x4 zacc = (f32x4){0.f, 0.f, 0.f, 0.f};
    #pragma unroll
    for (int qt = 0; qt < 2; ++qt) {
        f32x4 sacc[4];
        #pragma unroll
        for (int ct = 0; ct < 4; ++ct)
            sacc[ct] = __builtin_amdgcn_mfma_f32_16x16x32_bf16(
                kf[ct], qf[qt], zacc, 0, 0, 0);

        // lane-local max (v_max3-friendly tree)
        float tm[4];
        #pragma unroll
        for (int ct = 0; ct < 4; ++ct)
            tm[ct] = fmaxf(fmaxf(fmaxf(sacc[ct][0], sacc[ct][1]),
                                 sacc[ct][2]), sacc[ct][3]);
        const float mxl = fmaxf(fmaxf(fmaxf(tm[0], tm[1]), tm[2]), tm[3]);

        // defer-max: uniform-gated; common path has no shfl and no rescale
        if (__any(mxl > m_i[qt] + 8.f)) {
            float mx = fmaxf(mxl, __shfl_xor(mxl, 16, 64));
            mx = fmaxf(mx, __shfl_xor(mx, 32, 64));
            const float mnew = fmaxf(m_i[qt], mx);
            const float aq = fexp2(m_i[qt] - mnew);
            m_i[qt] = mnew;
            #pragma unroll
            for (int dt = 0; dt < 2; ++dt)
                #pragma unroll
                for (int r = 0; r < 4; ++r) oacc[dt][qt][r] *= aq;
            #pragma unroll
            for (int r = 0; r < 4; ++r) lacc[qt][r] *= aq;
        }
        const float mcur = m_i[qt];
        unsigned int pw[4][2];         // [tile][word] packed bf16 pairs
        #pragma unroll
        for (int ct = 0; ct < 4; ++ct) {
            float p[4];
            #pragma unroll
            for (int r = 0; r < 4; ++r) p[r] = fexp2(sacc[ct][r] - mcur);
            pw[ct][0] = (__float_as_uint(p[0]) >> 16) |
                        (__float_as_uint(p[1]) & 0xffff0000u);
            pw[ct][1] = (__float_as_uint(p[2]) >> 16) |
                        (__float_as_uint(p[3]) & 0xffff0000u);
        }

        // O^T += V^T·P^T ; l += 1^T·P^T (matrix pipe)
        #pragma unroll
        for (int kc = 0; kc < 2; ++kc) {
            union { unsigned int u[4]; bf16x8 v; } bw;
            bw.u[0] = pw[kc * 2 + 0][0];
            bw.u[1] = pw[kc * 2 + 0][1];
            bw.u[2] = pw[kc * 2 + 1][0];
            bw.u[3] = pw[kc * 2 + 1][1];
            oacc[0][qt] = __builtin_amdgcn_mfma_f32_16x16x32_bf16(
                vf[0 * 2 + kc], bw.v, oacc[0][qt], 0, 0, 0);
            oacc[1][qt] = __builtin_amdgcn_mfma_f32_16x16x32_bf16(
                vf[1 * 2 + kc], bw.v, oacc[1][qt], 0, 0, 0);
            lacc[qt] = __builtin_amdgcn_mfma_f32_16x16x32_bf16(
                onesv, bw.v, lacc[qt], 0, 0, 0);
        }
    }
}

// load one KV tile's fragments (K permuted rows; V flattened [dt*2+kc])
#define LOADT(KF, VF, KV) do {                                                  \
    KF[0] = *(const bf16x8*)&Kp[(size_t)((KV) + rowperm +  0) * Dx + g * 8];    \
    KF[1] = *(const bf16x8*)&Kp[(size_t)((KV) + rowperm +  4) * Dx + g * 8];    \
    KF[2] = *(const bf16x8*)&Kp[(size_t)((KV) + rowperm + 32) * Dx + g * 8];    \
    KF[3] = *(const bf16x8*)&Kp[(size_t)((KV) + rowperm + 36) * Dx + g * 8];    \
    VF[0] = *(const bf16x8*)&Vp[(size_t)(c)      * Nx + (KV)      + g * 8];     \
    VF[1] = *(const bf16x8*)&Vp[(size_t)(c)      * Nx + (KV) + 32 + g * 8];     \
    VF[2] = *(const bf16x8*)&Vp[(size_t)(16 + c) * Nx + (KV)      + g * 8];     \
    VF[3] = *(const bf16x8*)&Vp[(size_t)(16 + c) * Nx + (KV) + 32 + g * 8];     \
} while (0)

// ---------------------------------------------------------------------------
// Kernel 2: MFMA flash attention, register-resident P, prefetch double-buffer.
// grid (16, 32, 4) with XCD-bijective swizzle (bh pinned to xcd = bh%8).
// Wave = 32 q rows, quarter KV range (512) in 8 tiles of 64.
// Next tile's K/V fragments are loaded while the current tile computes (T14).
// Outputs: bf16 partial O^T + (m,l) per z.
// ---------------------------------------------------------------------------
__global__ __launch_bounds__(256, 4) void attn_kernel(
    const unsigned short* __restrict__ Qb, const unsigned short* __restrict__ Kb,
    const unsigned short* __restrict__ Vb, unsigned short* __restrict__ Opart,
    float2* __restrict__ ML)
{
    const int t  = threadIdx.x;
    const int wv = t >> 6, l = t & 63;
    const int g  = l >> 4, c = l & 15;

    // swizzle: bh pinned to xcd = bh & 7
    const int lin = blockIdx.x + 16 * blockIdx.y + 512 * blockIdx.z;  // 0..2047
    const int xcd = lin & 7, s = lin >> 3;          // s in 0..255
    const int bh = ((s & 3) << 3) | xcd;
    const int qt_ = (s >> 2) & 15;
    const int z  = s >> 6;                          // 0..3
    const int q0 = qt_ * 128 + wv * 32;

    const unsigned short* Qp = Qb + (size_t)bh * Nx * Dx;
    const unsigned short* Kp = Kb + (size_t)bh * Nx * Dx;
    const unsigned short* Vp = Vb + (size_t)bh * Dx * Nx;

    // Q fragments (B operand): lane holds Q[q0+qt*16+c][g*8 .. +8)
    bf16x8 qf[2];
    #pragma unroll
    for (int qt = 0; qt < 2; ++qt)
        qf[qt] = *(const bf16x8*)&Qp[(size_t)(q0 + qt * 16 + c) * Dx + g * 8];

    // ones fragment (bf16 1.0 x8) for the l-sum MFMA
    union { unsigned int u[4]; bf16x8 v; } onesf;
    onesf.u[0] = onesf.u[1] = onesf.u[2] = onesf.u[3] = 0x3F803F80u;

    f32x4 oacc[2][2];                          // [dt][qt]
    f32x4 lacc[2];                             // [qt]
    #pragma unroll
    for (int i = 0; i < 2; ++i) {
        lacc[i] = (f32x4){0.f, 0.f, 0.f, 0.f};
        #pragma unroll
        for (int j = 0; j < 2; ++j)
            oacc[i][j] = (f32x4){0.f, 0.f, 0.f, 0.f};
    }
    float m_i[2] = {-3.0e38f, -3.0e38f};

    const int rowperm = (c >> 2) * 8 + (c & 3);   // permuted K row for tile 0
    const int kv_beg = z * 512;

    bf16x8 kfA[4], vfA[4], kfB[4], vfB[4];
    LOADT(kfA, vfA, kv_beg);
    int kv0 = kv_beg;
    #pragma unroll
    for (int it = 0; it < 8; ++it) {
        if ((it & 1) == 0) {
            if (it < 7) { LOADT(kfB, vfB, kv0 + 64); }
            attn_tile(kfA, vfA, qf, onesf.v, oacc, lacc, m_i);
        } else {
            if (it < 7) { LOADT(kfA, vfA, kv0 + 64); }
            attn_tile(kfB, vfB, qf, onesf.v, oacc, lacc, m_i);
        }
        kv0 += 64;
    }

    // epilogue: store bf16 partial O^T + (m,l), layouts [z][bh][q][d] / [z][bh][q]
    unsigned short* Op = Opart + ((size_t)(z * 32 + bh)) * Nx * Dx;
    float2* Mlp = ML + (size_t)(z * 32 + bh) * Nx;
    #pragma unroll
    for (int qt = 0; qt < 2; ++qt) {
        const int q = q0 + qt * 16 + c;
        if (g == 0) Mlp[q] = make_float2(m_i[qt], lacc[qt][0]);
        #pragma unroll
        for (int dt = 0; dt < 2; ++dt) {
            ushort4 w4;
            w4.x = f2bf(oacc[dt][qt][0]);
            w4.y = f2bf(oacc[dt][qt][1]);
            w4.z = f2bf(oacc[dt][qt][2]);
            w4.w = f2bf(oacc[dt][qt][3]);
            *(ushort4*)&Op[(size_t)q * Dx + dt * 16 + g * 4] = w4;
        }
    }
}

// ---------------------------------------------------------------------------
// Kernel 3: fused {4-way KV-split merge + proj MFMA GEMM + bias + residual +
// LayerNorm}.  grid (128, 4): n-tile 16, b.  Block 256 = 4 waves,
// wave = 64 o x 16 n.  Merged A-fragment built on the fly from Opart + ML.
// ---------------------------------------------------------------------------
__global__ __launch_bounds__(256) void proj_ln_kernel(
    const unsigned short* __restrict__ Opart, const float2* __restrict__ ML,
    const unsigned short* __restrict__ Wpb,
    const float* __restrict__ bp, const float* __restrict__ x,
    const float* __restrict__ lng, const float* __restrict__ lnb,
    float* __restrict__ out)
{
    __shared__ float red[4][16];
    __shared__ float redq[4][16];
    __shared__ float mv[2][16];

    const int t  = threadIdx.x;
    const int wv = t >> 6, l = t & 63;
    const int lg = l >> 4, lc = l & 15;
    const int n0 = blockIdx.x * 16;
    const int b  = blockIdx.y;
    const int o0 = wv * 64;
    const int n  = n0 + lc;

    f32x4 acc[4];
    #pragma unroll
    for (int i = 0; i < 4; ++i) acc[i] = (f32x4){0.f, 0.f, 0.f, 0.f};

    for (int cc = 0; cc < Cx; cc += 32) {
        const int h = cc >> 5;
        const int bh = b * 8 + h;
        // 4-way merge weights for (bh, n)
        float2 e[4];
        #pragma unroll
        for (int zz = 0; zz < 4; ++zz)
            e[zz] = ML[(size_t)(zz * 32 + bh) * Nx + n];
        const float M = fmaxf(fmaxf(e[0].x, e[1].x), fmaxf(e[2].x, e[3].x));
        float a[4], den = 0.f;
        #pragma unroll
        for (int zz = 0; zz < 4; ++zz) {
            a[zz] = fexp2(e[zz].x - M);
            den += e[zz].y * a[zz];
        }
        const float inv = frcp(den);
        #pragma unroll
        for (int zz = 0; zz < 4; ++zz) a[zz] *= inv;

        // merged A fragment: 8 bf16 at d = lg*8 .. +8
        const size_t obase = ((size_t)bh * Nx + n) * Dx + lg * 8;
        union { uint4 q; unsigned int w[4]; } uz[4];
        #pragma unroll
        for (int zz = 0; zz < 4; ++zz)
            uz[zz].q = *(const uint4*)&Opart[(size_t)zz * 32 * Nx * Dx + obase];
        union { unsigned int u[4]; bf16x8 v; } af;
        #pragma unroll
        for (int wi = 0; wi < 4; ++wi) {
            float lo = 0.f, hi = 0.f;
            #pragma unroll
            for (int zz = 0; zz < 4; ++zz) {
                const unsigned int w = uz[zz].w[wi];
                lo = fmaf(__uint_as_float(w << 16), a[zz], lo);
                hi = fmaf(__uint_as_float(w & 0xffff0000u), a[zz], hi);
            }
            af.u[wi] = (unsigned int)f2bf(lo) | ((unsigned int)f2bf(hi) << 16);
        }
        // W fragments + MFMA
        #pragma unroll
        for (int ti = 0; ti < 4; ++ti) {
            const bf16x8 wf = *(const bf16x8*)
                &Wpb[(size_t)(o0 + ti * 16 + lc) * Cx + cc + lg * 8];
            acc[ti] = __builtin_amdgcn_mfma_f32_16x16x32_bf16(wf, af.v, acc[ti], 0, 0, 0);
        }
    }

    // bias + residual (o = o0+ti*16+lg*4+r, col n)
    #pragma unroll
    for (int ti = 0; ti < 4; ++ti) {
        const int o = o0 + ti * 16 + lg * 4;
        const float4 bv = *(const float4*)&bp[o];
        const float* xp = &x[((size_t)b * Cx + o) * Nx + n];
        acc[ti][0] += bv.x + xp[0];
        acc[ti][1] += bv.y + xp[Nx];
        acc[ti][2] += bv.z + xp[2 * Nx];
        acc[ti][3] += bv.w + xp[3 * Nx];
    }

    // column sums over this wave's 64 o
    float s_ = 0.f, q_ = 0.f;
    #pragma unroll
    for (int ti = 0; ti < 4; ++ti)
        #pragma unroll
        for (int r = 0; r < 4; ++r) {
            const float v = acc[ti][r];
            s_ += v; q_ += v * v;
        }
    s_ += __shfl_xor(s_, 16, 64);
    s_ += __shfl_xor(s_, 32, 64);
    q_ += __shfl_xor(q_, 16, 64);
    q_ += __shfl_xor(q_, 32, 64);
    if (lg == 0) { red[wv][lc] = s_; redq[wv][lc] = q_; }
    __syncthreads();
    if (t < 16) {
        const float S = red[0][t] + red[1][t] + red[2][t] + red[3][t];
        const float Q = redq[0][t] + redq[1][t] + redq[2][t] + redq[3][t];
        const float mu  = S * (1.f / 256.f);
        const float var = Q * (1.f / 256.f) - mu * mu;
        mv[0][t] = mu;
        mv[1][t] = rsqrtf(var + 1e-5f);
    }
    __syncthreads();

    const float mu_ = mv[0][lc], rs_ = mv[1][lc];
    #pragma unroll
    for (int ti = 0; ti < 4; ++ti) {
        const int o = o0 + ti * 16 + lg * 4;
        const float4 g4 = *(const float4*)&lng[o];
        const float4 b4 = *(const float4*)&lnb[o];
        const float gr[4] = {g4.x, g4.y, g4.z, g4.w};
        const float br[4] = {b4.x, b4.y, b4.z, b4.w};
        float* op = &out[((size_t)b * Cx + o) * Nx + n];
        #pragma unroll
        for (int r = 0; r < 4; ++r)
            op[(size_t)r * Nx] = (acc[ti][r] - mu_) * rs_ * gr[r] + br[r];
    }
}

// ---------------------------------------------------------------------------
extern "C" void kernel_launch(void* const* d_in, const int* in_sizes, int n_in,
                              void* d_out, int out_size, void* d_ws, size_t ws_size,
                              hipStream_t stream) {
    (void)in_sizes; (void)n_in; (void)out_size; (void)ws_size;
    const float* x      = (const float*)d_in[0];
    const float* w_qkv  = (const float*)d_in[1];
    const float* b_qkv  = (const float*)d_in[2];
    const float* w_proj = (const float*)d_in[3];
    const float* b_proj = (const float*)d_in[4];
    const float* ln_g   = (const float*)d_in[5];
    const float* ln_b   = (const float*)d_in[6];
    float* out = (float*)d_out;

    // workspace (31 MB extent; <= 32 MB proven in round 2).
    // Opart aliases Xt (Xt dead after qkv; Opart first written by attn):
    //   Xt    @0      [b][n][c] bf16        4 MB   (convert->qkv)
    //   Opart @0      [4z][bh][n][d] bf16  16 MB   (attn->proj)
    //   ML    @16MB   [4z][bh][n] float2    2 MB
    //   Wqkvb @18MB   [768][256] bf16     384 KB   (Q rows pre-scaled)
    //   Wpb   @18.375 [256][256] bf16     128 KB
    //   Qb    @19MB   [bh][n][d] bf16       4 MB
    //   Kb    @23MB   [bh][n][d] bf16       4 MB
    //   Vb    @27MB   [bh][d][n] bf16       4 MB   (ends at 31 MB)
    char* wsb = (char*)d_ws;
    unsigned short* Xt    = (unsigned short*)(wsb);
    unsigned short* Opart = (unsigned short*)(wsb);
    float2*         ML    = (float2*)(wsb + (size_t)16 * 1024 * 1024);
    unsigned short* Wqkvb = (unsigned short*)(wsb + (size_t)18 * 1024 * 1024);
    unsigned short* Wpb   = (unsigned short*)(wsb + (size_t)18 * 1024 * 1024 + 393216);
    unsigned short* Qb    = (unsigned short*)(wsb + (size_t)19 * 1024 * 1024);
    unsigned short* Kb    = (unsigned short*)(wsb + (size_t)23 * 1024 * 1024);
    unsigned short* Vb    = (unsigned short*)(wsb + (size_t)27 * 1024 * 1024);

    convert_kernel<<<dim3(640), 256, 0, stream>>>(x, w_qkv, w_proj, Xt, Wqkvb, Wpb);
    qkv_kernel<<<dim3(12, 16, 4), 256, 0, stream>>>(Wqkvb, Xt, b_qkv, Qb, Kb, Vb);
    attn_kernel<<<dim3(16, 32, 4), 256, 0, stream>>>(Qb, Kb, Vb, Opart, ML);
    proj_ln_kernel<<<dim3(128, 4), 256, 0, stream>>>(Opart, ML, Wpb, b_proj, x,
                                                     ln_g, ln_b, out);
}

// Round 10
// 158.720 us; speedup vs baseline: 1.0279x; 1.0279x over previous
//
#include <hip/hip_runtime.h>
#include <hip/hip_bf16.h>

// Problem constants (fixed by reference): B=4, C=256, N=2048, H=8, D=32
#define Bx 4
#define Cx 256
#define Nx 2048
#define Hx 8
#define Dx 32

typedef __attribute__((ext_vector_type(8))) short bf16x8;   // 8 bf16 (4 VGPRs)
typedef __attribute__((ext_vector_type(4))) float f32x4;

// attention scale folded with log2(e): (1/sqrt(32)) * 1.4426950408889634
#define QSCALE 0.25503494f

static __device__ __forceinline__ unsigned short f2bf(float f) {
    unsigned int u = __float_as_uint(f);
    u += 0x7fffu + ((u >> 16) & 1u);
    return (unsigned short)(u >> 16);
}
static __device__ __forceinline__ float bf2f(unsigned short u) {
    return __uint_as_float(((unsigned int)u) << 16);
}
// raw hardware exp2 / rcp (no libm range fixup)
static __device__ __forceinline__ float fexp2(float x) {
    float r;
    asm("v_exp_f32 %0, %1" : "=v"(r) : "v"(x));
    return r;
}
static __device__ __forceinline__ float frcp(float x) {
    float r;
    asm("v_rcp_f32 %0, %1" : "=v"(r) : "v"(x));
    return r;
}

// ---------------------------------------------------------------------------
// Kernel 0: convert inputs to bf16 MFMA layouts.  (unchanged)
// ---------------------------------------------------------------------------
__global__ __launch_bounds__(256) void convert_kernel(
    const float* __restrict__ x, const float* __restrict__ w_qkv,
    const float* __restrict__ w_proj,
    unsigned short* __restrict__ Xt, unsigned short* __restrict__ Wqkvb,
    unsigned short* __restrict__ Wpb)
{
    const int bx = blockIdx.x, t = threadIdx.x;
    if (bx < 512) {
        const int nb = (bx & 31) * 256 + t;      // 0..8191 over (b,n)
        const int b = nb >> 11, n = nb & 2047;
        const int c0 = (bx >> 5) * 16;           // 16 c-groups
        const float* xb = x + (size_t)b * Cx * Nx + n;
        unsigned short* dst = Xt + ((size_t)b * Nx + n) * Cx;
        #pragma unroll
        for (int c8 = 0; c8 < 16; c8 += 8) {
            float f[8];
            #pragma unroll
            for (int j = 0; j < 8; ++j) f[j] = xb[(size_t)(c0 + c8 + j) * Nx];
            uint4 pk;
            pk.x = (unsigned)f2bf(f[0]) | ((unsigned)f2bf(f[1]) << 16);
            pk.y = (unsigned)f2bf(f[2]) | ((unsigned)f2bf(f[3]) << 16);
            pk.z = (unsigned)f2bf(f[4]) | ((unsigned)f2bf(f[5]) << 16);
            pk.w = (unsigned)f2bf(f[6]) | ((unsigned)f2bf(f[7]) << 16);
            *(uint4*)&dst[c0 + c8] = pk;
        }
    } else {
        const int flat = (bx - 512) * 2048 + t * 8;
        #pragma unroll
        for (int hh = 0; hh < 8; hh += 4) {
            const int f0 = flat + hh;
            if (f0 < 768 * 256) {
                const float sc = (f0 < 65536) ? QSCALE : 1.0f;
                const float4 f = *(const float4*)&w_qkv[f0];
                ushort4 o;
                o.x = f2bf(f.x * sc); o.y = f2bf(f.y * sc);
                o.z = f2bf(f.z * sc); o.w = f2bf(f.w * sc);
                *(ushort4*)&Wqkvb[f0] = o;
            } else {
                const int f2v = f0 - 768 * 256;
                const float4 f = *(const float4*)&w_proj[f2v];
                ushort4 o;
                o.x = f2bf(f.x); o.y = f2bf(f.y);
                o.z = f2bf(f.z); o.w = f2bf(f.w);
                *(ushort4*)&Wpb[f2v] = o;
            }
        }
    }
}

// ---------------------------------------------------------------------------
// Kernel 1: QKV projection, MFMA, register-direct (no LDS).
// grid (12, 32, 4) = 1536 blocks (6 waves/SIMD); block 64o x 64n,
// wave tile = 32o x 32n.  XCD-bijective swizzle pins each (n-tile,b) to one XCD.
// region 0/1 (Q/K): D[o][n] = mfma(A=W, B=Xt)  -> Qb/Kb[bh][n][d]
// region 2   (V) : D[n][o] = mfma(A=Xt, B=W)  -> Vb[bh][d][n]
// ---------------------------------------------------------------------------
__global__ __launch_bounds__(256) void qkv_kernel(
    const unsigned short* __restrict__ Wb, const unsigned short* __restrict__ Xt,
    const float* __restrict__ bias,
    unsigned short* __restrict__ Qb, unsigned short* __restrict__ Kb,
    unsigned short* __restrict__ Vb)
{
    const int t = threadIdx.x;
    const int wv = t >> 6, l = t & 63;
    const int g = l >> 4, c = l & 15;

    const int lin = blockIdx.x + 12 * (blockIdx.y + 32 * blockIdx.z);  // 0..1535
    const int xcd = lin & 7, s = lin >> 3;          // s in 0..191
    const int xb = s % 12;
    const int yz = (s / 12) * 8 + xcd;              // 0..127
    const int yb = yz & 31, b = yz >> 5;

    const int o0 = xb * 64 + (wv >> 1) * 32;
    const int n0 = yb * 64 + (wv & 1) * 32;
    const int region = xb >> 2;                     // 0=Q, 1=K, 2=V

    const unsigned short* XtB = Xt + (size_t)b * Nx * Cx;

    f32x4 acc[2][2];
    #pragma unroll
    for (int i = 0; i < 2; ++i)
        #pragma unroll
        for (int j = 0; j < 2; ++j) acc[i][j] = (f32x4){0.f, 0.f, 0.f, 0.f};

    if (region < 2) {
        for (int cc = 0; cc < Cx; cc += 32) {
            bf16x8 wf[2], xf[2];
            #pragma unroll
            for (int ti = 0; ti < 2; ++ti)
                wf[ti] = *(const bf16x8*)&Wb[(size_t)(o0 + ti * 16 + c) * Cx + cc + g * 8];
            #pragma unroll
            for (int tj = 0; tj < 2; ++tj)
                xf[tj] = *(const bf16x8*)&XtB[(size_t)(n0 + tj * 16 + c) * Cx + cc + g * 8];
            #pragma unroll
            for (int ti = 0; ti < 2; ++ti)
                #pragma unroll
                for (int tj = 0; tj < 2; ++tj)
                    acc[ti][tj] = __builtin_amdgcn_mfma_f32_16x16x32_bf16(
                        wf[ti], xf[tj], acc[ti][tj], 0, 0, 0);
        }

        unsigned short* dst = (region == 0) ? Qb : Kb;
        #pragma unroll
        for (int ti = 0; ti < 2; ++ti) {
            const int o = o0 + ti * 16 + g * 4;
            float4 bv = *(const float4*)&bias[o];
            if (region == 0) { bv.x *= QSCALE; bv.y *= QSCALE; bv.z *= QSCALE; bv.w *= QSCALE; }
            const int d0 = o & 31, bh = b * 8 + ((o >> 5) & 7);
            unsigned short* dp = dst + (size_t)bh * Nx * Dx + d0;
            #pragma unroll
            for (int tj = 0; tj < 2; ++tj) {
                const int n = n0 + tj * 16 + c;
                ushort4 w4;
                w4.x = f2bf(acc[ti][tj][0] + bv.x);
                w4.y = f2bf(acc[ti][tj][1] + bv.y);
                w4.z = f2bf(acc[ti][tj][2] + bv.z);
                w4.w = f2bf(acc[ti][tj][3] + bv.w);
                *(ushort4*)&dp[(size_t)n * Dx] = w4;
            }
        }
    } else {
        for (int cc = 0; cc < Cx; cc += 32) {
            bf16x8 wf[2], xf[2];
            #pragma unroll
            for (int ot = 0; ot < 2; ++ot)
                wf[ot] = *(const bf16x8*)&Wb[(size_t)(o0 + ot * 16 + c) * Cx + cc + g * 8];
            #pragma unroll
            for (int nt = 0; nt < 2; ++nt)
                xf[nt] = *(const bf16x8*)&XtB[(size_t)(n0 + nt * 16 + c) * Cx + cc + g * 8];
            #pragma unroll
            for (int nt = 0; nt < 2; ++nt)
                #pragma unroll
                for (int ot = 0; ot < 2; ++ot)
                    acc[nt][ot] = __builtin_amdgcn_mfma_f32_16x16x32_bf16(
                        xf[nt], wf[ot], acc[nt][ot], 0, 0, 0);
        }

        #pragma unroll
        for (int ot = 0; ot < 2; ++ot) {
            const int o = o0 + ot * 16 + c;                   // 512..767
            const float bv = bias[o];
            const int oV = o - 512, d = oV & 31, bh = b * 8 + (oV >> 5);
            unsigned short* dp = Vb + ((size_t)bh * Dx + d) * Nx;
            #pragma unroll
            for (int nt = 0; nt < 2; ++nt) {
                const int n = n0 + nt * 16 + g * 4;
                ushort4 w4;
                w4.x = f2bf(acc[nt][ot][0] + bv);
                w4.y = f2bf(acc[nt][ot][1] + bv);
                w4.z = f2bf(acc[nt][ot][2] + bv);
                w4.w = f2bf(acc[nt][ot][3] + bv);
                *(ushort4*)&dp[n] = w4;
            }
        }
    }
}

// ---------------------------------------------------------------------------
// Kernel 2: MFMA flash attention (round-8 exact: z=2, no prefetch).
// grid (16, 32, 2) with XCD-bijective swizzle (bh pinned to xcd = bh%8).
// Wave = 32 q rows, half KV range in 16 tiles of 64.  Register-resident P
// (permuted-K trick), defer-max with lane-local precheck + __any gate,
// raw v_exp_f32, l via MFMA ones-trick.  Outputs: bf16 partial O^T + (m,l).
// ---------------------------------------------------------------------------
__global__ __launch_bounds__(256, 4) void attn_kernel(
    const unsigned short* __restrict__ Qb, const unsigned short* __restrict__ Kb,
    const unsigned short* __restrict__ Vb, unsigned short* __restrict__ Opart,
    float2* __restrict__ ML)
{
    const int t  = threadIdx.x;
    const int wv = t >> 6, l = t & 63;
    const int g  = l >> 4, c = l & 15;

    const int lin = blockIdx.x + 16 * blockIdx.y + 512 * blockIdx.z;
    const int xcd = lin & 7, s = lin >> 3;          // s in 0..127
    const int bh = ((s & 3) << 3) | xcd;
    const int qt_ = (s >> 2) & 15;
    const int z  = s >> 6;
    const int q0 = qt_ * 128 + wv * 32;

    const unsigned short* Qp = Qb + (size_t)bh * Nx * Dx;
    const unsigned short* Kp = Kb + (size_t)bh * Nx * Dx;
    const unsigned short* Vp = Vb + (size_t)bh * Dx * Nx;

    bf16x8 qf[2];
    #pragma unroll
    for (int qt = 0; qt < 2; ++qt)
        qf[qt] = *(const bf16x8*)&Qp[(size_t)(q0 + qt * 16 + c) * Dx + g * 8];

    union { unsigned int u[4]; bf16x8 v; } onesf;
    onesf.u[0] = onesf.u[1] = onesf.u[2] = onesf.u[3] = 0x3F803F80u;

    f32x4 oacc[2][2];                          // [dt][qt]
    f32x4 lacc[2];                             // [qt]
    #pragma unroll
    for (int i = 0; i < 2; ++i) {
        lacc[i] = (f32x4){0.f, 0.f, 0.f, 0.f};
        #pragma unroll
        for (int j = 0; j < 2; ++j)
            oacc[i][j] = (f32x4){0.f, 0.f, 0.f, 0.f};
    }
    float m_i[2] = {-3.0e38f, -3.0e38f};
    const f32x4 zacc = (f32x4){0.f, 0.f, 0.f, 0.f};

    const int rowperm = (c >> 2) * 8 + (c & 3);   // permuted K row for tile 0

    const int kv_beg = z * (Nx / 2), kv_end = kv_beg + (Nx / 2);
    for (int kv0 = kv_beg; kv0 < kv_end; kv0 += 64) {
        bf16x8 kf[4];
        kf[0] = *(const bf16x8*)&Kp[(size_t)(kv0 + rowperm +  0) * Dx + g * 8];
        kf[1] = *(const bf16x8*)&Kp[(size_t)(kv0 + rowperm +  4) * Dx + g * 8];
        kf[2] = *(const bf16x8*)&Kp[(size_t)(kv0 + rowperm + 32) * Dx + g * 8];
        kf[3] = *(const bf16x8*)&Kp[(size_t)(kv0 + rowperm + 36) * Dx + g * 8];
        bf16x8 vf[2][2];
        #pragma unroll
        for (int dt = 0; dt < 2; ++dt)
            #pragma unroll
            for (int kc = 0; kc < 2; ++kc)
                vf[dt][kc] = *(const bf16x8*)
                    &Vp[(size_t)(dt * 16 + c) * Nx + kv0 + kc * 32 + g * 8];

        #pragma unroll
        for (int qt = 0; qt < 2; ++qt) {
            f32x4 sacc[4];
            #pragma unroll
            for (int ct = 0; ct < 4; ++ct)
                sacc[ct] = __builtin_amdgcn_mfma_f32_16x16x32_bf16(
                    kf[ct], qf[qt], zacc, 0, 0, 0);

            float tm[4];
            #pragma unroll
            for (int ct = 0; ct < 4; ++ct)
                tm[ct] = fmaxf(fmaxf(fmaxf(sacc[ct][0], sacc[ct][1]),
                                     sacc[ct][2]), sacc[ct][3]);
            const float mxl = fmaxf(fmaxf(fmaxf(tm[0], tm[1]), tm[2]), tm[3]);

            if (__any(mxl > m_i[qt] + 8.f)) {
                float mx = fmaxf(mxl, __shfl_xor(mxl, 16, 64));
                mx = fmaxf(mx, __shfl_xor(mx, 32, 64));
                const float mnew = fmaxf(m_i[qt], mx);
                const float aq = fexp2(m_i[qt] - mnew);
                m_i[qt] = mnew;
                #pragma unroll
                for (int dt = 0; dt < 2; ++dt)
                    #pragma unroll
                    for (int r = 0; r < 4; ++r) oacc[dt][qt][r] *= aq;
                #pragma unroll
                for (int r = 0; r < 4; ++r) lacc[qt][r] *= aq;
            }
            const float mcur = m_i[qt];
            unsigned int pw[4][2];
            #pragma unroll
            for (int ct = 0; ct < 4; ++ct) {
                float p[4];
                #pragma unroll
                for (int r = 0; r < 4; ++r) p[r] = fexp2(sacc[ct][r] - mcur);
                pw[ct][0] = (__float_as_uint(p[0]) >> 16) |
                            (__float_as_uint(p[1]) & 0xffff0000u);
                pw[ct][1] = (__float_as_uint(p[2]) >> 16) |
                            (__float_as_uint(p[3]) & 0xffff0000u);
            }

            #pragma unroll
            for (int kc = 0; kc < 2; ++kc) {
                union { unsigned int u[4]; bf16x8 v; } bw;
                bw.u[0] = pw[kc * 2 + 0][0];
                bw.u[1] = pw[kc * 2 + 0][1];
                bw.u[2] = pw[kc * 2 + 1][0];
                bw.u[3] = pw[kc * 2 + 1][1];
                oacc[0][qt] = __builtin_amdgcn_mfma_f32_16x16x32_bf16(
                    vf[0][kc], bw.v, oacc[0][qt], 0, 0, 0);
                oacc[1][qt] = __builtin_amdgcn_mfma_f32_16x16x32_bf16(
                    vf[1][kc], bw.v, oacc[1][qt], 0, 0, 0);
                lacc[qt] = __builtin_amdgcn_mfma_f32_16x16x32_bf16(
                    onesf.v, bw.v, lacc[qt], 0, 0, 0);
            }
        }
    }

    unsigned short* Op = Opart + ((size_t)(z * 32 + bh)) * Nx * Dx;
    float2* Mlp = ML + (size_t)(z * 32 + bh) * Nx;
    #pragma unroll
    for (int qt = 0; qt < 2; ++qt) {
        const int q = q0 + qt * 16 + c;
        if (g == 0) Mlp[q] = make_float2(m_i[qt], lacc[qt][0]);
        #pragma unroll
        for (int dt = 0; dt < 2; ++dt) {
            ushort4 w4;
            w4.x = f2bf(oacc[dt][qt][0]);
            w4.y = f2bf(oacc[dt][qt][1]);
            w4.z = f2bf(oacc[dt][qt][2]);
            w4.w = f2bf(oacc[dt][qt][3]);
            *(ushort4*)&Op[(size_t)q * Dx + dt * 16 + g * 4] = w4;
        }
    }
}

// ---------------------------------------------------------------------------
// Kernel 3: fused {2-way merge (LDS-staged, once per block) + proj MFMA GEMM
// + bias + residual + LayerNorm}.  grid (128, 4): n-tile 16, b.
// Block 256 = 4 waves, wave = 64 o x 16 n.
// Merged A-tile [16n][256c] bf16 staged in LDS with XOR-swizzled c-groups
// (cgrp ^ (n&7)) -> b128 reads/writes spread uniformly over 8 bank-slots.
// ---------------------------------------------------------------------------
__global__ __launch_bounds__(256) void proj_ln_kernel(
    const unsigned short* __restrict__ Opart, const float2* __restrict__ ML,
    const unsigned short* __restrict__ Wpb,
    const float* __restrict__ bp, const float* __restrict__ x,
    const float* __restrict__ lng, const float* __restrict__ lnb,
    float* __restrict__ out)
{
    __shared__ uint4 Albs[16][32];   // [n][swizzled c-group of 8 bf16], 8 KB
    __shared__ float red[4][16];
    __shared__ float redq[4][16];
    __shared__ float mv[2][16];

    const int t  = threadIdx.x;
    const int wv = t >> 6, l = t & 63;
    const int lg = l >> 4, lc = l & 15;
    const int n0 = blockIdx.x * 16;
    const int b  = blockIdx.y;
    const int o0 = wv * 64;
    const int n  = n0 + lc;

    // ---- stage merged A tile (16 n x 256 c), once per block ----
    {
        const int n_s = t & 15;
        #pragma unroll
        for (int it = 0; it < 2; ++it) {
            const int cgrp = (t >> 4) + it * 16;        // 0..31
            const int h  = cgrp >> 2;
            const int bh = b * 8 + h;
            const int d8 = (cgrp & 3) * 8;
            const float2 e0 = ML[(size_t)bh * Nx + n0 + n_s];
            const float2 e1 = ML[(size_t)(32 + bh) * Nx + n0 + n_s];
            const float M  = fmaxf(e0.x, e1.x);
            const float a0 = fexp2(e0.x - M), a1 = fexp2(e1.x - M);
            const float inv = frcp(e0.y * a0 + e1.y * a1);
            const float w0 = a0 * inv, w1 = a1 * inv;
            const size_t obase = ((size_t)bh * Nx + n0 + n_s) * Dx + d8;
            union { uint4 q; unsigned int w[4]; } u0, u1;
            u0.q = *(const uint4*)&Opart[obase];
            u1.q = *(const uint4*)&Opart[(size_t)32 * Nx * Dx + obase];
            union { unsigned int u[4]; uint4 q; } af;
            #pragma unroll
            for (int wi = 0; wi < 4; ++wi) {
                const float lo = __uint_as_float(u0.w[wi] << 16) * w0 +
                                 __uint_as_float(u1.w[wi] << 16) * w1;
                const float hi = __uint_as_float(u0.w[wi] & 0xffff0000u) * w0 +
                                 __uint_as_float(u1.w[wi] & 0xffff0000u) * w1;
                af.u[wi] = (unsigned)f2bf(lo) | ((unsigned)f2bf(hi) << 16);
            }
            Albs[n_s][cgrp ^ (n_s & 7)] = af.q;
        }
    }
    __syncthreads();

    // ---- GEMM: acc[ti] over K, A from LDS, W from global ----
    f32x4 acc[4];
    #pragma unroll
    for (int i = 0; i < 4; ++i) acc[i] = (f32x4){0.f, 0.f, 0.f, 0.f};

    #pragma unroll
    for (int cc8 = 0; cc8 < 32; cc8 += 4) {      // cc8 = c/8; K-chunk 32
        union { uint4 q; bf16x8 v; } af;
        af.q = Albs[lc][(cc8 + lg) ^ (lc & 7)];
        #pragma unroll
        for (int ti = 0; ti < 4; ++ti) {
            const bf16x8 wf = *(const bf16x8*)
                &Wpb[(size_t)(o0 + ti * 16 + lc) * Cx + cc8 * 8 + lg * 8];
            acc[ti] = __builtin_amdgcn_mfma_f32_16x16x32_bf16(wf, af.v, acc[ti], 0, 0, 0);
        }
    }

    // bias + residual (o = o0+ti*16+lg*4+r, col n)
    #pragma unroll
    for (int ti = 0; ti < 4; ++ti) {
        const int o = o0 + ti * 16 + lg * 4;
        const float4 bv = *(const float4*)&bp[o];
        const float* xp = &x[((size_t)b * Cx + o) * Nx + n];
        acc[ti][0] += bv.x + xp[0];
        acc[ti][1] += bv.y + xp[Nx];
        acc[ti][2] += bv.z + xp[2 * Nx];
        acc[ti][3] += bv.w + xp[3 * Nx];
    }

    // column sums over this wave's 64 o
    float s_ = 0.f, q_ = 0.f;
    #pragma unroll
    for (int ti = 0; ti < 4; ++ti)
        #pragma unroll
        for (int r = 0; r < 4; ++r) {
            const float v = acc[ti][r];
            s_ += v; q_ += v * v;
        }
    s_ += __shfl_xor(s_, 16, 64);
    s_ += __shfl_xor(s_, 32, 64);
    q_ += __shfl_xor(q_, 16, 64);
    q_ += __shfl_xor(q_, 32, 64);
    if (lg == 0) { red[wv][lc] = s_; redq[wv][lc] = q_; }
    __syncthreads();
    if (t < 16) {
        const float S = red[0][t] + red[1][t] + red[2][t] + red[3][t];
        const float Q = redq[0][t] + redq[1][t] + redq[2][t] + redq[3][t];
        const float mu  = S * (1.f / 256.f);
        const float var = Q * (1.f / 256.f) - mu * mu;
        mv[0][t] = mu;
        mv[1][t] = rsqrtf(var + 1e-5f);
    }
    __syncthreads();

    const float mu_ = mv[0][lc], rs_ = mv[1][lc];
    #pragma unroll
    for (int ti = 0; ti < 4; ++ti) {
        const int o = o0 + ti * 16 + lg * 4;
        const float4 g4 = *(const float4*)&lng[o];
        const float4 b4 = *(const float4*)&lnb[o];
        const float gr[4] = {g4.x, g4.y, g4.z, g4.w};
        const float br[4] = {b4.x, b4.y, b4.z, b4.w};
        float* op = &out[((size_t)b * Cx + o) * Nx + n];
        #pragma unroll
        for (int r = 0; r < 4; ++r)
            op[(size_t)r * Nx] = (acc[ti][r] - mu_) * rs_ * gr[r] + br[r];
    }
}

// ---------------------------------------------------------------------------
extern "C" void kernel_launch(void* const* d_in, const int* in_sizes, int n_in,
                              void* d_out, int out_size, void* d_ws, size_t ws_size,
                              hipStream_t stream) {
    (void)in_sizes; (void)n_in; (void)out_size; (void)ws_size;
    const float* x      = (const float*)d_in[0];
    const float* w_qkv  = (const float*)d_in[1];
    const float* b_qkv  = (const float*)d_in[2];
    const float* w_proj = (const float*)d_in[3];
    const float* b_proj = (const float*)d_in[4];
    const float* ln_g   = (const float*)d_in[5];
    const float* ln_b   = (const float*)d_in[6];
    float* out = (float*)d_out;

    // workspace (22 MB extent).  Opart aliases Xt (dead after qkv):
    //   Xt    @0     [b][n][c] bf16        4 MB   (convert->qkv)
    //   Opart @0     [2z][bh][n][d] bf16   8 MB   (attn->proj)
    //   ML    @8MB   [2z][bh][n] float2    1 MB
    //   Wqkvb @9MB   [768][256] bf16     384 KB   (Q rows pre-scaled)
    //   Wpb   @9.4MB [256][256] bf16     128 KB
    //   Qb    @10MB  [bh][n][d] bf16       4 MB
    //   Kb    @14MB  [bh][n][d] bf16       4 MB
    //   Vb    @18MB  [bh][d][n] bf16       4 MB   (ends at 22 MB)
    char* wsb = (char*)d_ws;
    unsigned short* Xt    = (unsigned short*)(wsb);
    unsigned short* Opart = (unsigned short*)(wsb);
    float2*         ML    = (float2*)(wsb + (size_t)8 * 1024 * 1024);
    unsigned short* Wqkvb = (unsigned short*)(wsb + (size_t)9 * 1024 * 1024);
    unsigned short* Wpb   = (unsigned short*)(wsb + (size_t)9 * 1024 * 1024 + 393216);
    unsigned short* Qb    = (unsigned short*)(wsb + (size_t)10 * 1024 * 1024);
    unsigned short* Kb    = (unsigned short*)(wsb + (size_t)14 * 1024 * 1024);
    unsigned short* Vb    = (unsigned short*)(wsb + (size_t)18 * 1024 * 1024);

    convert_kernel<<<dim3(640), 256, 0, stream>>>(x, w_qkv, w_proj, Xt, Wqkvb, Wpb);
    qkv_kernel<<<dim3(12, 32, 4), 256, 0, stream>>>(Wqkvb, Xt, b_qkv, Qb, Kb, Vb);
    attn_kernel<<<dim3(16, 32, 2), 256, 0, stream>>>(Qb, Kb, Vb, Opart, ML);
    proj_ln_kernel<<<dim3(128, 4), 256, 0, stream>>>(Opart, ML, Wpb, b_proj, x,
                                                     ln_g, ln_b, out);
}